// Round 11
// baseline (321.500 us; speedup 1.0000x reference)
//
#include <hip/hip_runtime.h>

namespace {

typedef float f4v __attribute__((ext_vector_type(4)));
typedef float f2v __attribute__((ext_vector_type(2)));
typedef unsigned short ushort_t;

constexpr int MM = 3;
constexpr int BB = 16384;
constexpr int DD = 1024;
constexpr int CC = 100;
constexpr int HH = 2048;             // 2*DD
constexpr int DESIRED = BB / CC;     // 163
constexpr int NB  = BB / 256;        // 64 label blocks
constexpr int SSMAX = 43;            // cap (scpart allocation)
constexpr int RU  = 8;               // row unroll

// base matvec partition
constexpr int DBS   = 4;
constexpr int NBASE = (HH / 256) * DBS * MM;  // 96
// class-GEMM geometry (W2 read exactly once)
constexpr int KC  = 4, JL = HH / KC;    // 512 j per block
constexpr int DG2 = 4,  DR2 = 256;
constexpr int CSPL = 4, CH = CC / CSPL; // 4x25 class split

// ws byte offsets
constexpr size_t WS_COUNTS = 0;          // 128 int
constexpr size_t WS_GEN    = 512;        // 128 int
constexpr size_t WS_OFF    = 1024;       // 128 int
constexpr size_t WS_BHIST  = 4096;       // NB*128 int (32 KB)
constexpr size_t WS_BPART  = 36864;      // DBS*MM*HH f32 (96 KB) -> ends 135168
constexpr size_t WS_SCPART = 135168;     // SSMAX*MM*2*128 f32 (132 KB) -> 267264
constexpr size_t WS_GPART  = 270336;     // MM*DG2*KC*CC*DR2 bf16 (2.4 MB) -> 2727936
constexpr size_t WS_PSUM   = 2727936;    // SS*MM*CC*DD bf16 (runtime-sized)
constexpr size_t WS_ACT    = 2727936;    // act f32 (2.4 MB) aliases psum head;
                                         // dead before k_copysum runs

__device__ __forceinline__ float bits2f(unsigned u) {
  union { unsigned i; float f; } x; x.i = u; return x.f;
}
__device__ __forceinline__ ushort_t f2bf(float f) {
  union { float f; unsigned i; } x; x.f = f;
  unsigned r = x.i + 0x7FFFu + ((x.i >> 16) & 1u);
  return (ushort_t)(r >> 16);
}
__device__ __forceinline__ unsigned pack2bf(float a, float b) {
  return (unsigned)f2bf(a) | ((unsigned)f2bf(b) << 16);
}
__device__ __forceinline__ float bf2f(ushort_t u) {
  return bits2f(((unsigned)u) << 16);
}

// L1: per-block label histogram + head labels || base matvec partials.
__global__ void __launch_bounds__(256)
k_hist_base(const int* __restrict__ labels, const float* __restrict__ fused,
            const float* __restrict__ W1, int* __restrict__ bhist,
            float* __restrict__ bpart, float* __restrict__ out_lab) {
  int bid = blockIdx.x, t = threadIdx.x;
  if (bid < NB) {
    __shared__ int h[128];
    if (t < 128) h[t] = 0;
    __syncthreads();
    int b = bid * 256 + t;
    int l = labels[b];
    atomicAdd(&h[l], 1);
    out_lab[b] = (float)l;
    __syncthreads();
    if (t < 128) bhist[bid * 128 + t] = h[t];
  } else {
    int b3 = bid - NB;
    int jb = b3 % (HH / 256), db = (b3 / (HH / 256)) % DBS,
        m = b3 / ((HH / 256) * DBS);
    int j = jb * 256 + t;
    const float* w = W1 + ((size_t)m * (DD + CC)) * HH + j;
    float acc = 0.f;
    int dlo = db * (DD / DBS);
#pragma unroll 8
    for (int d = dlo; d < dlo + DD / DBS; ++d)
      acc = fmaf(fused[d], w[(size_t)d * HH], acc);
    bpart[((size_t)db * MM + m) * HH + j] = acc;
  }
}

// L2: block 0 = plan; blocks 1..300 = LN-activation -> act[m][j][c].
__global__ void __launch_bounds__(256)
k_plan_act(const int* __restrict__ bhist, const float* __restrict__ W1,
           const float* __restrict__ b1, const float* __restrict__ lng,
           const float* __restrict__ lnb, const float* __restrict__ bpart,
           int* __restrict__ counts, int* __restrict__ gen,
           int* __restrict__ off, float* __restrict__ act,
           float* __restrict__ out_lab_tail, float* __restrict__ out_loss,
           const float* __restrict__ dw, int N) {
  __shared__ float r1[256], r2[256];
  int bid = blockIdx.x, t = threadIdx.x;
  if (bid == 0) {
    __shared__ int s[128], soff[CC + 1];
    int run = 0;
    if (t < 128) {
      for (int blk = 0; blk < NB; ++blk) run += bhist[blk * 128 + t];
      counts[t] = run;
    }
    int cnt = (t < CC) ? run : 0;
    int g = (t < CC && cnt > 0) ? max(DESIRED - cnt, 0) : 0;
    if (t < 128) s[t] = g;
    __syncthreads();
    for (int o = 1; o < 128; o <<= 1) {
      int v = (t < 128 && t >= o) ? s[t - o] : 0;
      __syncthreads();
      if (t < 128) s[t] += v;
      __syncthreads();
    }
    if (t < CC) {
      int excl = s[t] - g;
      gen[t] = g;
      off[t] = excl;
      soff[t] = excl;
    }
    if (t == 0) {
      soff[CC] = N;
      *out_loss = (N > 0) ? 0.1f * dw[0] : 0.0f;
    }
    __syncthreads();
    for (int i = t; i < N; i += 256) {
      int lo = 0, hi = CC;
      while (hi - lo > 1) {
        int mid = (lo + hi) >> 1;
        if (soff[mid] <= i) lo = mid; else hi = mid;
      }
      out_lab_tail[i] = (float)lo;
    }
  } else {
    int b2 = bid - 1;
    int c = b2 % CC, m = b2 / CC;
    const float* w1row = W1 + ((size_t)m * (DD + CC) + DD + c) * HH;
    float h[8];
    float s = 0.f, s2 = 0.f;
#pragma unroll
    for (int k = 0; k < 8; ++k) {
      int j = t + k * 256;
      float base = bpart[(size_t)(0 * MM + m) * HH + j]
                 + bpart[(size_t)(1 * MM + m) * HH + j]
                 + bpart[(size_t)(2 * MM + m) * HH + j]
                 + bpart[(size_t)(3 * MM + m) * HH + j];
      float v = base + w1row[j] + b1[m * HH + j];
      h[k] = v; s += v; s2 += v * v;
    }
    r1[t] = s; r2[t] = s2;
    __syncthreads();
    for (int o = 128; o > 0; o >>= 1) {
      if (t < o) { r1[t] += r1[t + o]; r2[t] += r2[t + o]; }
      __syncthreads();
    }
    float mu = r1[0] * (1.f / HH);
    float var = r2[0] * (1.f / HH) - mu * mu;
    float rstd = rsqrtf(var + 1e-5f);
    float* ao = act + (size_t)m * HH * CC;
#pragma unroll
    for (int k = 0; k < 8; ++k) {
      int j = t + k * 256;
      float v = (h[k] - mu) * rstd * lng[m * HH + j] + lnb[m * HH + j];
      v = v > 0.f ? v : 0.2f * v;
      ao[(size_t)j * CC + c] = v;   // [m][j][c] for uniform scalar gemm reads
    }
  }
}

// L3: gpart[m][dg][kc][c][d'] (bf16) = sum_{j in chunk} act[m][j][c]*W2[m][j][d]
__global__ void __launch_bounds__(256)
k_gemm(const float* __restrict__ act, const float* __restrict__ W2,
       ushort_t* __restrict__ gpart) {
  int dg = blockIdx.x, kc = blockIdx.y;
  int m = blockIdx.z >> 2, ch = blockIdx.z & 3;
  int t = threadIdx.x;
  int d = dg * DR2 + t;
  int j0 = kc * JL, c0 = ch * CH;
  float acc2[CH];
#pragma unroll
  for (int c = 0; c < CH; ++c) acc2[c] = 0.f;
  const float* ab = act + ((size_t)m * HH + j0) * CC + c0;
  const float* wb = W2 + ((size_t)m * HH + j0) * DD + d;
  for (int j = 0; j < JL; ++j) {
    float w2v = wb[(size_t)j * DD];
    const float* aj = ab + (size_t)j * CC;   // uniform -> scalar loads
#pragma unroll
    for (int c = 0; c < CH; ++c) acc2[c] = fmaf(aj[c], w2v, acc2[c]);
  }
  ushort_t* pb = gpart + ((size_t)(m * DG2 + dg) * KC + kc) * (CC * DR2)
               + (size_t)c0 * DR2 + t;
#pragma unroll
  for (int c = 0; c < CH; ++c) pb[(size_t)c * DR2] = f2bf(acc2[c]);
}

// L4: balanced sequential copy + deterministic class-sum (packed-bf16 LDS).
// Block (h, m, s), 512 threads. Stripe rows split at mid:
//   loop1: block copies ITS rows fully (4KB seq read + write); upd-waves
//          (threads [h*256,(h+1)*256)) accumulate its d-half of those rows.
//   loop2: threads 0..255 read only the h-half cols (2KB seq) of the OTHER
//          rows and accumulate.
// Fixed order (own rows asc, then other rows asc); no atomics => deterministic.
__global__ void __launch_bounds__(512)
k_copysum(const float* __restrict__ feat, const int* __restrict__ labels,
          float* __restrict__ out, ushort_t* __restrict__ psum,
          float* __restrict__ scpart, int BN, int CHUNK) {
  __shared__ unsigned accp[CC][256];   // 100 KB packed 2xbf16
  __shared__ int slab[1024];
  int h = blockIdx.x, m = blockIdx.y, s = blockIdx.z;
  int t = threadIdx.x;
  int b0 = s * CHUNK;
  int nr = min(CHUNK, BB - b0);
  if (nr < 0) nr = 0;
  for (int i = t; i < CC * 256; i += 512) (&accp[0][0])[i] = 0u;
  for (int i = t; i < nr; i += 512) slab[i] = labels[b0 + i];
  __syncthreads();
  int mid = nr >> 1;
  bool upd = (t >> 8) == h;          // wave-uniform
  int j = t & 255;
  const float* fb = feat + ((size_t)m * BB + b0) * DD + 2 * t;
  float* ob = out + ((size_t)m * BN + b0) * DD + 2 * t;
  // ---- loop1: own rows, full width ----
  {
    int rs = (h == 0) ? 0 : mid, re = (h == 0) ? mid : nr;
    int r = rs;
    for (; r + RU <= re; r += RU) {
      f2v v[RU];
#pragma unroll
      for (int k = 0; k < RU; ++k)
        v[k] = *(const f2v*)(fb + (size_t)(r + k) * DD);
#pragma unroll
      for (int k = 0; k < RU; ++k)
        *(f2v*)(ob + (size_t)(r + k) * DD) = v[k];
      if (upd) {
#pragma unroll
        for (int k = 0; k < RU; ++k) {
          int c = slab[r + k];
          unsigned u = accp[c][j];
          accp[c][j] = pack2bf(bits2f(u << 16) + v[k].x,
                               bits2f(u & 0xFFFF0000u) + v[k].y);
        }
      }
    }
    for (; r < re; ++r) {
      f2v v = *(const f2v*)(fb + (size_t)r * DD);
      *(f2v*)(ob + (size_t)r * DD) = v;
      if (upd) {
        int c = slab[r];
        unsigned u = accp[c][j];
        accp[c][j] = pack2bf(bits2f(u << 16) + v.x,
                             bits2f(u & 0xFFFF0000u) + v.y);
      }
    }
  }
  // ---- loop2: other rows, own half only (threads 0..255) ----
  if (t < 256) {
    const float* fb2 = feat + ((size_t)m * BB + b0) * DD + h * 512 + 2 * t;
    int os = (h == 0) ? mid : 0, oe = (h == 0) ? nr : mid;
    int r = os;
    for (; r + RU <= oe; r += RU) {
      f2v v[RU];
#pragma unroll
      for (int k = 0; k < RU; ++k)
        v[k] = *(const f2v*)(fb2 + (size_t)(r + k) * DD);
#pragma unroll
      for (int k = 0; k < RU; ++k) {
        int c = slab[r + k];
        unsigned u = accp[c][t];
        accp[c][t] = pack2bf(bits2f(u << 16) + v[k].x,
                             bits2f(u & 0xFFFF0000u) + v[k].y);
      }
    }
    for (; r < oe; ++r) {
      f2v v = *(const f2v*)(fb2 + (size_t)r * DD);
      int c = slab[r];
      unsigned u = accp[c][t];
      accp[c][t] = pack2bf(bits2f(u << 16) + v.x,
                           bits2f(u & 0xFFFF0000u) + v.y);
    }
  }
  __syncthreads();
  // flush psum half (bf16) + scpart (f32, fixed order)
  ushort_t* pb = psum + ((size_t)(s * MM + m) * CC) * DD + h * 512;
  for (int i = t; i < CC * 256; i += 512) {
    int c = i >> 8, jj = i & 255;
    *(unsigned*)(pb + (size_t)c * DD + 2 * jj) = accp[c][jj];
  }
  if (t < CC) {
    float ssum = 0.f;
    for (int jj = 0; jj < 256; ++jj) {
      unsigned u = accp[t][jj];
      ssum += bits2f(u << 16) + bits2f(u & 0xFFFF0000u);
    }
    scpart[(size_t)((s * MM + m) * 2 + h) * 128 + t] = ssum;
  }
}

// L5: g = sum_kc gpart + b2; proto = f32-sum of psum stripes / cnt;
//     mask from scpart; blend; scatter to gen rows of class c.
__global__ void __launch_bounds__(256)
k_final2(const ushort_t* __restrict__ gpart, const ushort_t* __restrict__ psum,
         const float* __restrict__ scpart, const int* __restrict__ counts,
         const float* __restrict__ b2, const float* __restrict__ corr,
         const int* __restrict__ gen, const int* __restrict__ off,
         float* __restrict__ out, int BN, int SS) {
  int c = blockIdx.x, m = blockIdx.y, t = threadIdx.x;
  int g = gen[c];
  if (g == 0) return;
  int d0 = t * 4, dg = d0 >> 8, dsub = d0 & 255;
  f4v a = {0.f, 0.f, 0.f, 0.f};
#pragma unroll
  for (int kc = 0; kc < KC; ++kc) {
    const ushort_t* q = &gpart[((size_t)(m * DG2 + dg) * KC + kc) * (CC * DR2)
                               + c * DR2 + dsub];
    a.x += bf2f(q[0]); a.y += bf2f(q[1]); a.z += bf2f(q[2]); a.w += bf2f(q[3]);
  }
  a += *(const f4v*)(&b2[m * DD + d0]);
  int oms[2];
  { int k = 0;
#pragma unroll
    for (int om = 0; om < MM; ++om) if (om != m) oms[k++] = om; }
  int cnt = counts[c];
  float inv = cnt > 0 ? 1.f / (float)cnt : 0.f;
  f4v pom[2];
#pragma unroll
  for (int k = 0; k < 2; ++k) {
    f4v p = {0.f, 0.f, 0.f, 0.f};
    for (int s = 0; s < SS; ++s) {
      const ushort_t* q = &psum[((size_t)(s * MM + oms[k]) * CC + c) * DD + d0];
      p.x += bf2f(q[0]); p.y += bf2f(q[1]); p.z += bf2f(q[2]); p.w += bf2f(q[3]);
    }
    p *= inv;
    pom[k] = p;
  }
  __shared__ float red[2][256];
  float p0 = 0.f, p1 = 0.f;
  for (int i = t; i < SS * 2; i += 256) {
    int s = i >> 1, hh = i & 1;
    p0 += scpart[(size_t)((s * MM + oms[0]) * 2 + hh) * 128 + c];
    p1 += scpart[(size_t)((s * MM + oms[1]) * 2 + hh) * 128 + c];
  }
  red[0][t] = p0; red[1][t] = p1;
  __syncthreads();
  for (int o = 128; o > 0; o >>= 1) {
    if (t < o) { red[0][t] += red[0][t + o]; red[1][t] += red[1][t + o]; }
    __syncthreads();
  }
#pragma unroll
  for (int k = 0; k < 2; ++k) {
    float al = corr[m * MM + oms[k]] * (red[k][0] > 0.f ? 1.f : 0.f);
    float ia = 1.f - al;
    a = a * ia + pom[k] * al;
  }
  int row0 = BB + off[c];
  for (int k = 0; k < g; ++k)
    *(f4v*)(&out[((size_t)m * BN + row0 + k) * DD + d0]) = a;
}

}  // namespace

extern "C" void kernel_launch(void* const* d_in, const int* in_sizes, int n_in,
                              void* d_out, int out_size, void* d_ws, size_t ws_size,
                              hipStream_t stream) {
  const float* features = (const float*)d_in[0];
  const float* fused    = (const float*)d_in[1];
  const int*   labels   = (const int*)d_in[2];
  const float* W1       = (const float*)d_in[3];
  const float* b1       = (const float*)d_in[4];
  const float* lng      = (const float*)d_in[5];
  const float* lnb      = (const float*)d_in[6];
  const float* W2       = (const float*)d_in[7];
  const float* b2       = (const float*)d_in[8];
  const float* corr     = (const float*)d_in[9];
  const float* dw       = (const float*)d_in[10];
  float* out = (float*)d_out;
  char*  ws  = (char*)d_ws;

  const int BN = (out_size - 1) / (MM * DD + 1);  // B + N
  const int N  = BN - BB;
  const size_t L0 = (size_t)MM * BN * DD;         // start of combined_labels

  // runtime stripe count from available workspace (deterministic per session)
  const size_t stripe_bytes = (size_t)MM * CC * DD * 2;  // 0.614 MB
  int SS = SSMAX;
  if (ws_size > WS_PSUM) {
    size_t fit = (ws_size - WS_PSUM) / stripe_bytes;
    if ((size_t)SS > fit) SS = (int)fit;
  } else {
    SS = 16;
  }
  if (SS < 16) SS = 16;
  const int CHUNK = (BB + SS - 1) / SS;

  int*      counts = (int*)(ws + WS_COUNTS);
  int*      gen    = (int*)(ws + WS_GEN);
  int*      off    = (int*)(ws + WS_OFF);
  int*      bhist  = (int*)(ws + WS_BHIST);
  float*    bpart  = (float*)(ws + WS_BPART);
  float*    scpart = (float*)(ws + WS_SCPART);
  ushort_t* gpart  = (ushort_t*)(ws + WS_GPART);
  float*    act    = (float*)(ws + WS_ACT);   // dead before k_copysum
  ushort_t* psum   = (ushort_t*)(ws + WS_PSUM);

  k_hist_base<<<NB + NBASE, 256, 0, stream>>>(labels, fused, W1, bhist, bpart,
                                              out + L0);
  k_plan_act<<<1 + CC * MM, 256, 0, stream>>>(bhist, W1, b1, lng, lnb, bpart,
                                              counts, gen, off, act,
                                              out + L0 + BB, out + L0 + BN,
                                              dw, N);
  k_gemm<<<dim3(DG2, KC, MM * CSPL), 256, 0, stream>>>(act, W2, gpart);
  k_copysum<<<dim3(2, MM, SS), 512, 0, stream>>>(features, labels, out, psum,
                                                 scpart, BN, CHUNK);
  k_final2<<<dim3(CC, MM), 256, 0, stream>>>(gpart, psum, scpart, counts, b2,
                                             corr, gen, off, out, BN, SS);
}

// Round 12
// 190.194 us; speedup vs baseline: 1.6904x; 1.6904x over previous
//
#include <hip/hip_runtime.h>

namespace {

typedef float f4v __attribute__((ext_vector_type(4)));

constexpr int MM = 3;
constexpr int BB = 16384;
constexpr int DD = 1024;
constexpr int CC = 100;
constexpr int HH = 2048;             // 2*DD
constexpr int DESIRED = BB / CC;     // 163
constexpr int RLS = 2048;            // rowlist stride per class
constexpr int RS  = 4;               // gather row-chunks per (c,m)
constexpr int NB  = BB / 256;        // 64 label blocks

// gather partition (solo kernel — mixing streams into it costs 20-30%)
constexpr int NGATH = CC * MM * RS;           // 1200
// base matvec partition (rides in hist kernel)
constexpr int DBS   = 4;
constexpr int NBASE = (HH / 256) * DBS * MM;  // 96
// class-GEMM geometry (W2 read exactly once)
constexpr int KC  = 8, JL = HH / KC;    // 256 j per block
constexpr int DG2 = 4,  DR2 = 256;
constexpr int CSPL = 4, CH = CC / CSPL; // 4x25 class split
constexpr int NGEMM = DG2 * KC * MM * CSPL;   // 384

// ws byte offsets (round-8-proven layout, 18.2 MB total)
constexpr size_t WS_COUNTS  = 0;         // 128 int
constexpr size_t WS_GEN     = 512;       // 128 int
constexpr size_t WS_OFF     = 1024;      // 128 int
constexpr size_t WS_BHIST   = 4096;      // NB*128 int (32 KB)
constexpr size_t WS_BLKBASE = 36864;     // NB*128 int (32 KB)
constexpr size_t WS_BPART   = 69632;     // DBS*MM*HH f32 (96 KB)
constexpr size_t WS_ROWLIST = 167936;    // CC*RLS int (800 KB)
constexpr size_t WS_ACT     = 987136;    // MM*HH*CC f32 (2.4 MB)
constexpr size_t WS_PSUM    = 3444736;   // CC*MM*RS*DD f32 (4.9 MB)
constexpr size_t WS_GPART   = 8359936;   // MM*DG2*KC*CC*DR2 f32 (9.83 MB)

// L1: per-block label histogram + head labels || base matvec partials.
__global__ void __launch_bounds__(256)
k_hist_base(const int* __restrict__ labels, const float* __restrict__ fused,
            const float* __restrict__ W1, int* __restrict__ bhist,
            float* __restrict__ bpart, float* __restrict__ out_lab) {
  int bid = blockIdx.x, t = threadIdx.x;
  if (bid < NB) {
    __shared__ int h[128];
    if (t < 128) h[t] = 0;
    __syncthreads();
    int b = bid * 256 + t;
    int l = labels[b];
    atomicAdd(&h[l], 1);
    out_lab[b] = (float)l;
    __syncthreads();
    if (t < 128) bhist[bid * 128 + t] = h[t];
  } else {
    // bpart[db][m][j] = sum_{d in chunk} fused[d] * W1[m][d][j]
    int b3 = bid - NB;
    int jb = b3 % (HH / 256), db = (b3 / (HH / 256)) % DBS,
        m = b3 / ((HH / 256) * DBS);
    int j = jb * 256 + t;
    const float* w = W1 + ((size_t)m * (DD + CC)) * HH + j;
    float acc = 0.f;
    int dlo = db * (DD / DBS);
#pragma unroll 8
    for (int d = dlo; d < dlo + DD / DBS; ++d)
      acc = fmaf(fused[d], w[(size_t)d * HH], acc);
    bpart[((size_t)db * MM + m) * HH + j] = acc;
  }
}

// L2: block 0 = plan (blkbase/counts/gen/off, tail labels, loss);
//     blocks 1..300 = LN-activation -> act[m][j][c].
__global__ void __launch_bounds__(256)
k_plan_act(const int* __restrict__ bhist, const float* __restrict__ W1,
           const float* __restrict__ b1, const float* __restrict__ lng,
           const float* __restrict__ lnb, const float* __restrict__ bpart,
           int* __restrict__ blkbase, int* __restrict__ counts,
           int* __restrict__ gen, int* __restrict__ off,
           float* __restrict__ act, float* __restrict__ out_lab_tail,
           float* __restrict__ out_loss, const float* __restrict__ dw, int N) {
  __shared__ float r1[256], r2[256];
  int bid = blockIdx.x, t = threadIdx.x;
  if (bid == 0) {
    __shared__ int s[128], soff[CC + 1];
    int run = 0;
    if (t < 128) {
      for (int blk = 0; blk < NB; ++blk) {
        blkbase[blk * 128 + t] = run;
        run += bhist[blk * 128 + t];
      }
      counts[t] = run;
    }
    int cnt = (t < CC) ? run : 0;
    int g = (t < CC && cnt > 0) ? max(DESIRED - cnt, 0) : 0;
    if (t < 128) s[t] = g;
    __syncthreads();
    for (int o = 1; o < 128; o <<= 1) {
      int v = (t < 128 && t >= o) ? s[t - o] : 0;
      __syncthreads();
      if (t < 128) s[t] += v;
      __syncthreads();
    }
    if (t < CC) {
      int excl = s[t] - g;
      gen[t] = g;
      off[t] = excl;
      soff[t] = excl;
    }
    if (t == 0) {
      soff[CC] = N;
      *out_loss = (N > 0) ? 0.1f * dw[0] : 0.0f;
    }
    __syncthreads();
    for (int i = t; i < N; i += 256) {
      int lo = 0, hi = CC;
      while (hi - lo > 1) {
        int mid = (lo + hi) >> 1;
        if (soff[mid] <= i) lo = mid; else hi = mid;
      }
      out_lab_tail[i] = (float)lo;
    }
  } else {
    // h = base + W1[m][D+c] + b1 -> LN -> leaky -> act[m][j][c]
    int b2 = bid - 1;
    int c = b2 % CC, m = b2 / CC;
    const float* w1row = W1 + ((size_t)m * (DD + CC) + DD + c) * HH;
    float h[8];
    float s = 0.f, s2 = 0.f;
#pragma unroll
    for (int k = 0; k < 8; ++k) {
      int j = t + k * 256;
      float base = bpart[(size_t)(0 * MM + m) * HH + j]
                 + bpart[(size_t)(1 * MM + m) * HH + j]
                 + bpart[(size_t)(2 * MM + m) * HH + j]
                 + bpart[(size_t)(3 * MM + m) * HH + j];
      float v = base + w1row[j] + b1[m * HH + j];
      h[k] = v; s += v; s2 += v * v;
    }
    r1[t] = s; r2[t] = s2;
    __syncthreads();
    for (int o = 128; o > 0; o >>= 1) {
      if (t < o) { r1[t] += r1[t + o]; r2[t] += r2[t + o]; }
      __syncthreads();
    }
    float mu = r1[0] * (1.f / HH);
    float var = r2[0] * (1.f / HH) - mu * mu;
    float rstd = rsqrtf(var + 1e-5f);
    float* ao = act + (size_t)m * HH * CC;
#pragma unroll
    for (int k = 0; k < 8; ++k) {
      int j = t + k * 256;
      float v = (h[k] - mu) * rstd * lng[m * HH + j] + lnb[m * HH + j];
      v = v > 0.f ? v : 0.2f * v;
      ao[(size_t)j * CC + c] = v;   // [m][j][c] for uniform scalar gemm reads
    }
  }
}

// L3: stable counting-sort scatter (blocks 0..63, deterministic rowlist)
//     || class-GEMM (blocks 64..447): gpart = act^T x W2, W2 read once.
__global__ void __launch_bounds__(256)
k_scatter_gemm(const int* __restrict__ labels, const int* __restrict__ blkbase,
               int* __restrict__ rowlist, const float* __restrict__ act,
               const float* __restrict__ W2, float* __restrict__ gpart) {
  int bid = blockIdx.x, t = threadIdx.x;
  if (bid < NB) {
    __shared__ int lab[256];
    int b = bid * 256 + t;
    int myl = labels[b];
    lab[t] = myl;
    __syncthreads();
    int rank = 0;
    for (int u = 0; u < t; ++u) rank += (lab[u] == myl) ? 1 : 0;
    int pos = blkbase[bid * 128 + myl] + rank;
    if (pos < RLS) rowlist[myl * RLS + pos] = b;
  } else {
    // gpart[m][dg][kc][c][d'] = sum_{j in kc-chunk} act[m][j][c] * W2[m][j][d]
    int idx = bid - NB;
    int dg = idx & (DG2 - 1);
    int kc = (idx >> 2) & (KC - 1);
    int z = idx >> 5;                 // DG2*KC = 32
    int m = z >> 2, ch = z & 3;
    int d = dg * DR2 + t;
    int j0 = kc * JL, c0 = ch * CH;
    float acc[CH];
#pragma unroll
    for (int c = 0; c < CH; ++c) acc[c] = 0.f;
    const float* ab = act + ((size_t)m * HH + j0) * CC + c0;
    const float* wb = W2 + ((size_t)m * HH + j0) * DD + d;
    for (int j = 0; j < JL; ++j) {
      float w2v = wb[(size_t)j * DD];
      const float* aj = ab + (size_t)j * CC;   // uniform -> scalar loads
#pragma unroll
      for (int c = 0; c < CH; ++c) acc[c] = fmaf(aj[c], w2v, acc[c]);
    }
    float* pb = gpart + ((size_t)(m * DG2 + dg) * KC + kc) * (CC * DR2)
              + (size_t)c0 * DR2 + t;
#pragma unroll
    for (int c = 0; c < CH; ++c) pb[(size_t)c * DR2] = acc[c];
  }
}

// L4: fused copy + register class-sum gather. SOLO kernel — measured 2.62 TB/s;
// any spatially-mixed second stream costs 20-30% (rounds 4/8/9/11).
__global__ void __launch_bounds__(256)
k_gather(const float* __restrict__ feat, const int* __restrict__ rowlist,
         const int* __restrict__ counts, float* __restrict__ out,
         float* __restrict__ psum, int BN) {
  int bid = blockIdx.x, t = threadIdx.x;
  int c = bid % CC, mrs = bid / CC;
  int m = mrs % MM, rs = mrs / MM;
  int cnt = min(counts[c], RLS);
  int lo = (cnt * rs) / RS, hi = (cnt * (rs + 1)) / RS;
  const int* rl = rowlist + c * RLS;
  int d0 = t * 4;
  const float* fb = feat + (size_t)m * BB * DD + d0;
  float* ob = out + (size_t)m * BN * DD + d0;
  f4v a = {0.f, 0.f, 0.f, 0.f};
  int i = lo;
  for (; i + 8 <= hi; i += 8) {
    int r0 = rl[i + 0], r1 = rl[i + 1], r2 = rl[i + 2], r3 = rl[i + 3];
    int r4 = rl[i + 4], r5 = rl[i + 5], r6 = rl[i + 6], r7 = rl[i + 7];
    const f4v v0 = *(const f4v*)(fb + (size_t)r0 * DD);
    const f4v v1 = *(const f4v*)(fb + (size_t)r1 * DD);
    const f4v v2 = *(const f4v*)(fb + (size_t)r2 * DD);
    const f4v v3 = *(const f4v*)(fb + (size_t)r3 * DD);
    const f4v v4 = *(const f4v*)(fb + (size_t)r4 * DD);
    const f4v v5 = *(const f4v*)(fb + (size_t)r5 * DD);
    const f4v v6 = *(const f4v*)(fb + (size_t)r6 * DD);
    const f4v v7 = *(const f4v*)(fb + (size_t)r7 * DD);
    *(f4v*)(ob + (size_t)r0 * DD) = v0;
    *(f4v*)(ob + (size_t)r1 * DD) = v1;
    *(f4v*)(ob + (size_t)r2 * DD) = v2;
    *(f4v*)(ob + (size_t)r3 * DD) = v3;
    *(f4v*)(ob + (size_t)r4 * DD) = v4;
    *(f4v*)(ob + (size_t)r5 * DD) = v5;
    *(f4v*)(ob + (size_t)r6 * DD) = v6;
    *(f4v*)(ob + (size_t)r7 * DD) = v7;
    a += v0 + v1 + v2 + v3 + v4 + v5 + v6 + v7;
  }
  for (; i < hi; ++i) {
    int r = rl[i];
    const f4v v = *(const f4v*)(fb + (size_t)r * DD);
    *(f4v*)(ob + (size_t)r * DD) = v;
    a += v;
  }
  *(f4v*)(&psum[(((size_t)c * MM + m) * RS + rs) * DD + d0]) = a;
}

// L5: g = sum_kc gpart + b2; proto+mask inline from psum (fixed-tree reduce);
//     blend; scatter to the gen rows of class c.
__global__ void __launch_bounds__(256)
k_final2(const float* __restrict__ gpart, const float* __restrict__ psum,
         const int* __restrict__ counts, const float* __restrict__ b2,
         const float* __restrict__ corr, const int* __restrict__ gen,
         const int* __restrict__ off, float* __restrict__ out, int BN) {
  int c = blockIdx.x, m = blockIdx.y, t = threadIdx.x;
  int g = gen[c];
  if (g == 0) return;
  int d0 = t * 4, dg = d0 >> 8, dsub = d0 & 255;
  f4v a = {0.f, 0.f, 0.f, 0.f};
#pragma unroll
  for (int kc = 0; kc < KC; ++kc)
    a += *(const f4v*)(&gpart[((size_t)(m * DG2 + dg) * KC + kc) * (CC * DR2)
                              + c * DR2 + dsub]);
  a += *(const f4v*)(&b2[m * DD + d0]);
  int oms[2];
  { int k = 0;
#pragma unroll
    for (int om = 0; om < MM; ++om) if (om != m) oms[k++] = om; }
  int cnt = counts[c];
  float inv = cnt > 0 ? 1.f / (float)cnt : 0.f;
  __shared__ float red[2][256];
  f4v pom[2];
#pragma unroll
  for (int k = 0; k < 2; ++k) {
    f4v p = {0.f, 0.f, 0.f, 0.f};
#pragma unroll
    for (int rs = 0; rs < RS; ++rs)
      p += *(const f4v*)(&psum[(((size_t)c * MM + oms[k]) * RS + rs) * DD + d0]);
    p *= inv;
    pom[k] = p;
    red[k][t] = p.x + p.y + p.z + p.w;
  }
  __syncthreads();
  for (int o = 128; o > 0; o >>= 1) {
    if (t < o) { red[0][t] += red[0][t + o]; red[1][t] += red[1][t + o]; }
    __syncthreads();
  }
#pragma unroll
  for (int k = 0; k < 2; ++k) {
    float al = corr[m * MM + oms[k]] * (red[k][0] > 0.f ? 1.f : 0.f);
    float ia = 1.f - al;
    a = a * ia + pom[k] * al;
  }
  int row0 = BB + off[c];
  for (int k = 0; k < g; ++k)
    *(f4v*)(&out[((size_t)m * BN + row0 + k) * DD + d0]) = a;
}

}  // namespace

extern "C" void kernel_launch(void* const* d_in, const int* in_sizes, int n_in,
                              void* d_out, int out_size, void* d_ws, size_t ws_size,
                              hipStream_t stream) {
  const float* features = (const float*)d_in[0];
  const float* fused    = (const float*)d_in[1];
  const int*   labels   = (const int*)d_in[2];
  const float* W1       = (const float*)d_in[3];
  const float* b1       = (const float*)d_in[4];
  const float* lng      = (const float*)d_in[5];
  const float* lnb      = (const float*)d_in[6];
  const float* W2       = (const float*)d_in[7];
  const float* b2       = (const float*)d_in[8];
  const float* corr     = (const float*)d_in[9];
  const float* dw       = (const float*)d_in[10];
  float* out = (float*)d_out;
  char*  ws  = (char*)d_ws;

  const int BN = (out_size - 1) / (MM * DD + 1);  // B + N
  const int N  = BN - BB;
  const size_t L0 = (size_t)MM * BN * DD;         // start of combined_labels

  int*   counts  = (int*)(ws + WS_COUNTS);
  int*   gen     = (int*)(ws + WS_GEN);
  int*   off     = (int*)(ws + WS_OFF);
  int*   bhist   = (int*)(ws + WS_BHIST);
  int*   blkbase = (int*)(ws + WS_BLKBASE);
  float* bpart   = (float*)(ws + WS_BPART);
  int*   rowlist = (int*)(ws + WS_ROWLIST);
  float* act     = (float*)(ws + WS_ACT);
  float* psum    = (float*)(ws + WS_PSUM);
  float* gpart   = (float*)(ws + WS_GPART);

  k_hist_base<<<NB + NBASE, 256, 0, stream>>>(labels, fused, W1, bhist, bpart,
                                              out + L0);
  k_plan_act<<<1 + CC * MM, 256, 0, stream>>>(bhist, W1, b1, lng, lnb, bpart,
                                              blkbase, counts, gen, off, act,
                                              out + L0 + BB, out + L0 + BN,
                                              dw, N);
  k_scatter_gemm<<<NB + NGEMM, 256, 0, stream>>>(labels, blkbase, rowlist,
                                                 act, W2, gpart);
  k_gather<<<NGATH, 256, 0, stream>>>(features, rowlist, counts, out, psum, BN);
  k_final2<<<dim3(CC, MM), 256, 0, stream>>>(gpart, psum, counts, b2, corr,
                                             gen, off, out, BN);
}

// Round 13
// 166.616 us; speedup vs baseline: 1.9296x; 1.1415x over previous
//
#include <hip/hip_runtime.h>

namespace {

typedef float f4v __attribute__((ext_vector_type(4)));

constexpr int MM = 3;
constexpr int BB = 16384;
constexpr int DD = 1024;
constexpr int CC = 100;
constexpr int HH = 2048;             // 2*DD
constexpr int DESIRED = BB / CC;     // 163
constexpr int RLS = 2048;            // rowlist stride per class
constexpr int RS  = 4;               // gather row-chunks per (c,m)
constexpr int NB  = BB / 256;        // 64 label blocks

// gather partition (solo kernel — mixing streams into it costs 20-30%)
constexpr int NGATH = CC * MM * RS;           // 1200
// base matvec partition (rides in hist kernel)
constexpr int DBS   = 4;
constexpr int NBASE = (HH / 256) * DBS * MM;  // 96
// class-GEMM geometry
constexpr int KC  = 8, JL = HH / KC;    // 256 j per block
constexpr int DG2 = 4,  DR2 = 256;
constexpr int CSPL = 4, CH = CC / CSPL; // 4x25 class split

// ws byte offsets (round-8-proven layout, 18.2 MB total)
constexpr size_t WS_COUNTS  = 0;         // 128 int
constexpr size_t WS_GEN     = 512;       // 128 int
constexpr size_t WS_OFF     = 1024;      // 128 int
constexpr size_t WS_BHIST   = 4096;      // NB*128 int (32 KB)
constexpr size_t WS_BLKBASE = 36864;     // NB*128 int (32 KB)
constexpr size_t WS_BPART   = 69632;     // DBS*MM*HH f32 (96 KB)
constexpr size_t WS_ROWLIST = 167936;    // CC*RLS int (800 KB)
constexpr size_t WS_ACT     = 987136;    // MM*HH*CC f32 (2.4 MB)
constexpr size_t WS_PSUM    = 3444736;   // CC*MM*RS*DD f32 (4.9 MB)
constexpr size_t WS_GPART   = 8359936;   // MM*DG2*KC*CC*DR2 f32 (9.83 MB)

// L1: per-block label histogram + head labels || base matvec partials.
__global__ void __launch_bounds__(256)
k_hist_base(const int* __restrict__ labels, const float* __restrict__ fused,
            const float* __restrict__ W1, int* __restrict__ bhist,
            float* __restrict__ bpart, float* __restrict__ out_lab) {
  int bid = blockIdx.x, t = threadIdx.x;
  if (bid < NB) {
    __shared__ int h[128];
    if (t < 128) h[t] = 0;
    __syncthreads();
    int b = bid * 256 + t;
    int l = labels[b];
    atomicAdd(&h[l], 1);
    out_lab[b] = (float)l;
    __syncthreads();
    if (t < 128) bhist[bid * 128 + t] = h[t];
  } else {
    // bpart[db][m][j] = sum_{d in chunk} fused[d] * W1[m][d][j]
    int b3 = bid - NB;
    int jb = b3 % (HH / 256), db = (b3 / (HH / 256)) % DBS,
        m = b3 / ((HH / 256) * DBS);
    int j = jb * 256 + t;
    const float* w = W1 + ((size_t)m * (DD + CC)) * HH + j;
    float acc = 0.f;
    int dlo = db * (DD / DBS);
#pragma unroll 8
    for (int d = dlo; d < dlo + DD / DBS; ++d)
      acc = fmaf(fused[d], w[(size_t)d * HH], acc);
    bpart[((size_t)db * MM + m) * HH + j] = acc;
  }
}

// L2: block 0 = plan (blkbase/counts/gen/off, tail labels, loss);
//     blocks 1..300 = LN-activation -> act[m][j][c].
__global__ void __launch_bounds__(256)
k_plan_act(const int* __restrict__ bhist, const float* __restrict__ W1,
           const float* __restrict__ b1, const float* __restrict__ lng,
           const float* __restrict__ lnb, const float* __restrict__ bpart,
           int* __restrict__ blkbase, int* __restrict__ counts,
           int* __restrict__ gen, int* __restrict__ off,
           float* __restrict__ act, float* __restrict__ out_lab_tail,
           float* __restrict__ out_loss, const float* __restrict__ dw, int N) {
  __shared__ float r1[256], r2[256];
  int bid = blockIdx.x, t = threadIdx.x;
  if (bid == 0) {
    __shared__ int s[128], soff[CC + 1];
    int run = 0;
    if (t < 128) {
      for (int blk = 0; blk < NB; ++blk) {
        blkbase[blk * 128 + t] = run;
        run += bhist[blk * 128 + t];
      }
      counts[t] = run;
    }
    int cnt = (t < CC) ? run : 0;
    int g = (t < CC && cnt > 0) ? max(DESIRED - cnt, 0) : 0;
    if (t < 128) s[t] = g;
    __syncthreads();
    for (int o = 1; o < 128; o <<= 1) {
      int v = (t < 128 && t >= o) ? s[t - o] : 0;
      __syncthreads();
      if (t < 128) s[t] += v;
      __syncthreads();
    }
    if (t < CC) {
      int excl = s[t] - g;
      gen[t] = g;
      off[t] = excl;
      soff[t] = excl;
    }
    if (t == 0) {
      soff[CC] = N;
      *out_loss = (N > 0) ? 0.1f * dw[0] : 0.0f;
    }
    __syncthreads();
    for (int i = t; i < N; i += 256) {
      int lo = 0, hi = CC;
      while (hi - lo > 1) {
        int mid = (lo + hi) >> 1;
        if (soff[mid] <= i) lo = mid; else hi = mid;
      }
      out_lab_tail[i] = (float)lo;
    }
  } else {
    // h = base + W1[m][D+c] + b1 -> LN -> leaky -> act[m][j][c]
    int b2 = bid - 1;
    int c = b2 % CC, m = b2 / CC;
    const float* w1row = W1 + ((size_t)m * (DD + CC) + DD + c) * HH;
    float h[8];
    float s = 0.f, s2 = 0.f;
#pragma unroll
    for (int k = 0; k < 8; ++k) {
      int j = t + k * 256;
      float base = bpart[(size_t)(0 * MM + m) * HH + j]
                 + bpart[(size_t)(1 * MM + m) * HH + j]
                 + bpart[(size_t)(2 * MM + m) * HH + j]
                 + bpart[(size_t)(3 * MM + m) * HH + j];
      float v = base + w1row[j] + b1[m * HH + j];
      h[k] = v; s += v; s2 += v * v;
    }
    r1[t] = s; r2[t] = s2;
    __syncthreads();
    for (int o = 128; o > 0; o >>= 1) {
      if (t < o) { r1[t] += r1[t + o]; r2[t] += r2[t + o]; }
      __syncthreads();
    }
    float mu = r1[0] * (1.f / HH);
    float var = r2[0] * (1.f / HH) - mu * mu;
    float rstd = rsqrtf(var + 1e-5f);
    float* ao = act + (size_t)m * HH * CC;
#pragma unroll
    for (int k = 0; k < 8; ++k) {
      int j = t + k * 256;
      float v = (h[k] - mu) * rstd * lng[m * HH + j] + lnb[m * HH + j];
      v = v > 0.f ? v : 0.2f * v;
      ao[(size_t)j * CC + c] = v;   // [m][j][c] for uniform scalar gemm reads
    }
  }
}

// L3: stable counting-sort scatter — bit-deterministic rowlist (solo, proven).
__global__ void __launch_bounds__(256)
k_scatter(const int* __restrict__ labels, const int* __restrict__ blkbase,
          int* __restrict__ rowlist) {
  __shared__ int lab[256];
  int blk = blockIdx.x, t = threadIdx.x;
  int b = blk * 256 + t;
  int myl = labels[b];
  lab[t] = myl;
  __syncthreads();
  int rank = 0;
  for (int u = 0; u < t; ++u) rank += (lab[u] == myl) ? 1 : 0;
  int pos = blkbase[blk * 128 + myl] + rank;
  if (pos < RLS) rowlist[myl * RLS + pos] = b;
}

// L4: class-GEMM (solo): gpart[m][dg][kc][c][d'] = sum_j act[m][j][c]*W2[m][j][d]
__global__ void __launch_bounds__(256)
k_gemm(const float* __restrict__ act, const float* __restrict__ W2,
       float* __restrict__ gpart) {
  int dg = blockIdx.x, kc = blockIdx.y;
  int m = blockIdx.z >> 2, ch = blockIdx.z & 3;
  int t = threadIdx.x;
  int d = dg * DR2 + t;
  int j0 = kc * JL, c0 = ch * CH;
  float acc[CH];
#pragma unroll
  for (int c = 0; c < CH; ++c) acc[c] = 0.f;
  const float* ab = act + ((size_t)m * HH + j0) * CC + c0;
  const float* wb = W2 + ((size_t)m * HH + j0) * DD + d;
  for (int j = 0; j < JL; ++j) {
    float w2v = wb[(size_t)j * DD];
    const float* aj = ab + (size_t)j * CC;   // uniform -> scalar loads
#pragma unroll
    for (int c = 0; c < CH; ++c) acc[c] = fmaf(aj[c], w2v, acc[c]);
  }
  float* pb = gpart + ((size_t)(m * DG2 + dg) * KC + kc) * (CC * DR2)
            + (size_t)c0 * DR2 + t;
#pragma unroll
  for (int c = 0; c < CH; ++c) pb[(size_t)c * DR2] = acc[c];
}

// L5: fused copy + register class-sum gather. SOLO kernel (2.62 TB/s proven);
// NT ld/st on the row copy keeps L2/L3 clean (values order-independent;
// psum order fixed by deterministic rowlist => bit-stable replays).
__global__ void __launch_bounds__(256)
k_gather(const float* __restrict__ feat, const int* __restrict__ rowlist,
         const int* __restrict__ counts, float* __restrict__ out,
         float* __restrict__ psum, int BN) {
  int bid = blockIdx.x, t = threadIdx.x;
  int c = bid % CC, mrs = bid / CC;
  int m = mrs % MM, rs = mrs / MM;
  int cnt = min(counts[c], RLS);
  int lo = (cnt * rs) / RS, hi = (cnt * (rs + 1)) / RS;
  const int* rl = rowlist + c * RLS;
  int d0 = t * 4;
  const float* fb = feat + (size_t)m * BB * DD + d0;
  float* ob = out + (size_t)m * BN * DD + d0;
  f4v a = {0.f, 0.f, 0.f, 0.f};
  int i = lo;
  for (; i + 8 <= hi; i += 8) {
    int r0 = rl[i + 0], r1 = rl[i + 1], r2 = rl[i + 2], r3 = rl[i + 3];
    int r4 = rl[i + 4], r5 = rl[i + 5], r6 = rl[i + 6], r7 = rl[i + 7];
    const f4v v0 = __builtin_nontemporal_load((const f4v*)(fb + (size_t)r0 * DD));
    const f4v v1 = __builtin_nontemporal_load((const f4v*)(fb + (size_t)r1 * DD));
    const f4v v2 = __builtin_nontemporal_load((const f4v*)(fb + (size_t)r2 * DD));
    const f4v v3 = __builtin_nontemporal_load((const f4v*)(fb + (size_t)r3 * DD));
    const f4v v4 = __builtin_nontemporal_load((const f4v*)(fb + (size_t)r4 * DD));
    const f4v v5 = __builtin_nontemporal_load((const f4v*)(fb + (size_t)r5 * DD));
    const f4v v6 = __builtin_nontemporal_load((const f4v*)(fb + (size_t)r6 * DD));
    const f4v v7 = __builtin_nontemporal_load((const f4v*)(fb + (size_t)r7 * DD));
    __builtin_nontemporal_store(v0, (f4v*)(ob + (size_t)r0 * DD));
    __builtin_nontemporal_store(v1, (f4v*)(ob + (size_t)r1 * DD));
    __builtin_nontemporal_store(v2, (f4v*)(ob + (size_t)r2 * DD));
    __builtin_nontemporal_store(v3, (f4v*)(ob + (size_t)r3 * DD));
    __builtin_nontemporal_store(v4, (f4v*)(ob + (size_t)r4 * DD));
    __builtin_nontemporal_store(v5, (f4v*)(ob + (size_t)r5 * DD));
    __builtin_nontemporal_store(v6, (f4v*)(ob + (size_t)r6 * DD));
    __builtin_nontemporal_store(v7, (f4v*)(ob + (size_t)r7 * DD));
    a += v0 + v1 + v2 + v3 + v4 + v5 + v6 + v7;
  }
  for (; i < hi; ++i) {
    int r = rl[i];
    const f4v v = __builtin_nontemporal_load((const f4v*)(fb + (size_t)r * DD));
    __builtin_nontemporal_store(v, (f4v*)(ob + (size_t)r * DD));
    a += v;
  }
  *(f4v*)(&psum[(((size_t)c * MM + m) * RS + rs) * DD + d0]) = a;
}

// L6: g = sum_kc gpart + b2; proto+mask inline from psum (fixed-tree reduce);
//     blend; scatter to the gen rows of class c.
__global__ void __launch_bounds__(256)
k_final2(const float* __restrict__ gpart, const float* __restrict__ psum,
         const int* __restrict__ counts, const float* __restrict__ b2,
         const float* __restrict__ corr, const int* __restrict__ gen,
         const int* __restrict__ off, float* __restrict__ out, int BN) {
  int c = blockIdx.x, m = blockIdx.y, t = threadIdx.x;
  int g = gen[c];
  if (g == 0) return;
  int d0 = t * 4, dg = d0 >> 8, dsub = d0 & 255;
  f4v a = {0.f, 0.f, 0.f, 0.f};
#pragma unroll
  for (int kc = 0; kc < KC; ++kc)
    a += *(const f4v*)(&gpart[((size_t)(m * DG2 + dg) * KC + kc) * (CC * DR2)
                              + c * DR2 + dsub]);
  a += *(const f4v*)(&b2[m * DD + d0]);
  int oms[2];
  { int k = 0;
#pragma unroll
    for (int om = 0; om < MM; ++om) if (om != m) oms[k++] = om; }
  int cnt = counts[c];
  float inv = cnt > 0 ? 1.f / (float)cnt : 0.f;
  __shared__ float red[2][256];
  f4v pom[2];
#pragma unroll
  for (int k = 0; k < 2; ++k) {
    f4v p = {0.f, 0.f, 0.f, 0.f};
#pragma unroll
    for (int rs = 0; rs < RS; ++rs)
      p += *(const f4v*)(&psum[(((size_t)c * MM + oms[k]) * RS + rs) * DD + d0]);
    p *= inv;
    pom[k] = p;
    red[k][t] = p.x + p.y + p.z + p.w;
  }
  __syncthreads();
  for (int o = 128; o > 0; o >>= 1) {
    if (t < o) { red[0][t] += red[0][t + o]; red[1][t] += red[1][t + o]; }
    __syncthreads();
  }
#pragma unroll
  for (int k = 0; k < 2; ++k) {
    float al = corr[m * MM + oms[k]] * (red[k][0] > 0.f ? 1.f : 0.f);
    float ia = 1.f - al;
    a = a * ia + pom[k] * al;
  }
  int row0 = BB + off[c];
  for (int k = 0; k < g; ++k)
    *(f4v*)(&out[((size_t)m * BN + row0 + k) * DD + d0]) = a;
}

}  // namespace

extern "C" void kernel_launch(void* const* d_in, const int* in_sizes, int n_in,
                              void* d_out, int out_size, void* d_ws, size_t ws_size,
                              hipStream_t stream) {
  const float* features = (const float*)d_in[0];
  const float* fused    = (const float*)d_in[1];
  const int*   labels   = (const int*)d_in[2];
  const float* W1       = (const float*)d_in[3];
  const float* b1       = (const float*)d_in[4];
  const float* lng      = (const float*)d_in[5];
  const float* lnb      = (const float*)d_in[6];
  const float* W2       = (const float*)d_in[7];
  const float* b2       = (const float*)d_in[8];
  const float* corr     = (const float*)d_in[9];
  const float* dw       = (const float*)d_in[10];
  float* out = (float*)d_out;
  char*  ws  = (char*)d_ws;

  const int BN = (out_size - 1) / (MM * DD + 1);  // B + N
  const int N  = BN - BB;
  const size_t L0 = (size_t)MM * BN * DD;         // start of combined_labels

  int*   counts  = (int*)(ws + WS_COUNTS);
  int*   gen     = (int*)(ws + WS_GEN);
  int*   off     = (int*)(ws + WS_OFF);
  int*   bhist   = (int*)(ws + WS_BHIST);
  int*   blkbase = (int*)(ws + WS_BLKBASE);
  float* bpart   = (float*)(ws + WS_BPART);
  int*   rowlist = (int*)(ws + WS_ROWLIST);
  float* act     = (float*)(ws + WS_ACT);
  float* psum    = (float*)(ws + WS_PSUM);
  float* gpart   = (float*)(ws + WS_GPART);

  k_hist_base<<<NB + NBASE, 256, 0, stream>>>(labels, fused, W1, bhist, bpart,
                                              out + L0);
  k_plan_act<<<1 + CC * MM, 256, 0, stream>>>(bhist, W1, b1, lng, lnb, bpart,
                                              blkbase, counts, gen, off, act,
                                              out + L0 + BB, out + L0 + BN,
                                              dw, N);
  k_scatter<<<NB, 256, 0, stream>>>(labels, blkbase, rowlist);
  k_gemm<<<dim3(DG2, KC, MM * CSPL), 256, 0, stream>>>(act, W2, gpart);
  k_gather<<<NGATH, 256, 0, stream>>>(features, rowlist, counts, out, psum, BN);
  k_final2<<<dim3(CC, MM), 256, 0, stream>>>(gpart, psum, counts, b2, corr,
                                             gen, off, out, BN);
}